// Round 4
// baseline (89.600 us; speedup 1.0000x reference)
//
#include <hip/hip_runtime.h>
#include <stdint.h>
#include <math.h>

typedef __bf16 bf16;
typedef __bf16 bf16x8 __attribute__((ext_vector_type(8)));
typedef __bf16 bf16x4 __attribute__((ext_vector_type(4)));
typedef float f32x4 __attribute__((ext_vector_type(4)));

static constexpr int BATCH = 16384;
static constexpr int D_IN  = 1024;
static constexpr int UNITS = 512;
static constexpr int D_OUT = 512;

__device__ __forceinline__ void gll16(const void* g, void* l) {
    __builtin_amdgcn_global_load_lds(
        (const __attribute__((address_space(1))) void*)g,
        (__attribute__((address_space(3))) void*)l,
        16, 0, 0);
}

// ---------------- fused weight prep: one launch ----------------
__global__ __launch_bounds__(256)
void k_prep(const float* __restrict__ w_in, const float* __restrict__ sens_w,
            const float* __restrict__ ro_w,
            bf16* __restrict__ w_in_bf, bf16* __restrict__ sensT, bf16* __restrict__ ro_bf)
{
    __shared__ float tile[32][33];
    const int b = blockIdx.x;
    const int t = threadIdx.x;
    if (b < 512) {
        int i = b * 256 + t;
        f32x4 v = ((const f32x4*)w_in)[i];
        bf16x4 o = { (bf16)v.x, (bf16)v.y, (bf16)v.z, (bf16)v.w };
        ((bf16x4*)w_in_bf)[i] = o;
    } else if (b < 768) {
        int bb = b - 512;
        int bx = bb & 15, by = bb >> 4;
        int tx = t & 31, ty = t >> 5;
        #pragma unroll
        for (int j = ty; j < 32; j += 8)
            tile[j][tx] = sens_w[(size_t)(by * 32 + j) * UNITS + bx * 32 + tx];
        __syncthreads();
        #pragma unroll
        for (int j = ty; j < 32; j += 8)
            sensT[(size_t)(bx * 32 + j) * UNITS + by * 32 + tx] = (bf16)tile[tx][j];
    } else {
        int i = (b - 768) * 256 + t;
        f32x4 v = ((const f32x4*)ro_w)[i];
        bf16x4 o = { (bf16)v.x, (bf16)v.y, (bf16)v.z, (bf16)v.w };
        ((bf16x4*)ro_bf)[i] = o;
    }
}

// ---------------- fused GEMM, 8 waves, 2-phase dbuf, gll16 both operands ----------------
// C[M,N] = epilogue( A[M,K] @ Bw[N,K]^T + bias )
// AF32: A staged as fp32 via global_load_lds with XOR-swizzled source (rule 21,
//       involution q ^= (row&7)<<4 applied at stage AND read), cvt->bf16 in-reg.
// EPI 1: out_bf16 = tanh(.)
// EPI 2: a=sigmoid(.); out_f32 = a+(states-a)*exp(-0.1/tau)
// EPI 3: out_f32 = .
template<int K, int EPI, bool AF32>
__global__ __launch_bounds__(512, 4)
void k_gemm(const float* __restrict__ Af, const bf16* __restrict__ Ab,
            const bf16* __restrict__ Bw,
            const float* __restrict__ bias,
            const float* __restrict__ tau,
            const float* __restrict__ states,
            float* __restrict__ outF, bf16* __restrict__ outB,
            int M, int N)
{
    constexpr int ABPB = AF32 ? (128 * 32 * 4) : (128 * 32 * 2);  // A bytes/buffer
    __shared__ __align__(16) char sAraw[2][ABPB];
    __shared__ bf16 sB[2][128 * 32];

    const int t = threadIdx.x;
    const int ntiles = N >> 7;
    // XCD-aware swizzle (nwg % 8 == 0): same-m-strip blocks co-resident per XCD
    const int nwg = gridDim.x;
    const int d = blockIdx.x;
    const int bid = (d & 7) * (nwg >> 3) + (d >> 3);
    const int mtile = bid / ntiles;
    const int ntile = bid % ntiles;
    const int m0 = mtile << 7, n0 = ntile << 7;

    const int lane = t & 63;
    const int wave = t >> 6;            // 0..7 -> 4m x 2n sub-tiles of 32x64
    const int wr = (wave >> 1) * 32;
    const int wc = (wave & 1) * 64;
    const int l15 = lane & 15;
    const int lk  = (lane >> 4) * 8;    // k-elem offset of this lane's frag

    f32x4 acc[2][4];
    #pragma unroll
    for (int m = 0; m < 2; ++m)
        #pragma unroll
        for (int n = 0; n < 4; ++n)
            acc[m][n] = (f32x4){0.f, 0.f, 0.f, 0.f};

    // ---- staging addresses ----
    // B (bf16): thread t -> row t>>2, col (t&3)*8; one gll16 covers 128x32 bf16
    const int brow = t >> 2, bk8 = (t & 3) * 8;
    const bf16* bbp = Bw + (size_t)(n0 + brow) * K + bk8;
    // A fp32: thread t -> row t>>3 (per 64-row half), 16B slot (t&7), source
    // col-byte XOR-swizzled so linear LDS + swizzled read = correct data
    const int ar  = t >> 3;
    const int aqs = (((t & 7) ^ (ar & 7)) << 4);
    const char* ag0 = (const char*)Af + (size_t)(m0 + ar) * K * 4 + aqs;
    const char* ag1 = (const char*)Af + (size_t)(m0 + 64 + ar) * K * 4 + aqs;
    // A bf16: thread t -> row t>>2, col (t&3)*8 (same as B)
    const bf16* abp = Ab + (size_t)(m0 + brow) * K + bk8;

    auto STAGE = [&](int buf, int kt) {
        if constexpr (AF32) {
            gll16(ag0 + (size_t)kt * 4, &sAraw[buf][t * 16]);
            gll16(ag1 + (size_t)kt * 4, &sAraw[buf][8192 + t * 16]);
        } else {
            gll16(abp + kt, &((bf16*)sAraw[buf])[t * 8]);
        }
        gll16(bbp + kt, &sB[buf][t * 8]);
    };

    // ---- prologue ----
    STAGE(0, 0);
    __syncthreads();

    int cur = 0;
    for (int kt = 0; kt < K; kt += 32) {
        if (kt + 32 < K) STAGE(cur ^ 1, kt + 32);

        bf16x8 afr[2], bfr[4];
        if constexpr (AF32) {
            #pragma unroll
            for (int m = 0; m < 2; ++m) {
                const int r = wr + m * 16 + l15;
                const int s = (r & 7) << 4;
                const char* rb = &sAraw[cur][r * 128];
                f32x4 h0 = *(const f32x4*)(rb + ((lk * 4) ^ s));
                f32x4 h1 = *(const f32x4*)(rb + ((lk * 4 + 16) ^ s));
                afr[m] = (bf16x8){ (bf16)h0.x, (bf16)h0.y, (bf16)h0.z, (bf16)h0.w,
                                   (bf16)h1.x, (bf16)h1.y, (bf16)h1.z, (bf16)h1.w };
            }
        } else {
            #pragma unroll
            for (int m = 0; m < 2; ++m)
                afr[m] = *(const bf16x8*)&((const bf16*)sAraw[cur])[(wr + m * 16 + l15) * 32 + lk];
        }
        #pragma unroll
        for (int n = 0; n < 4; ++n)
            bfr[n] = *(const bf16x8*)&sB[cur][(wc + n * 16 + l15) * 32 + lk];

        #pragma unroll
        for (int m = 0; m < 2; ++m)
            #pragma unroll
            for (int n = 0; n < 4; ++n)
                acc[m][n] = __builtin_amdgcn_mfma_f32_16x16x32_bf16(
                                afr[m], bfr[n], acc[m][n], 0, 0, 0);

        __syncthreads();
        cur ^= 1;
    }

    // epilogue: D row = wr + 4*(lane>>4) + r (+16m), col = wc + l15 (+16n)
    const int rbase = m0 + wr + ((lane >> 4) << 2);
    const int cbase = n0 + wc + l15;
    #pragma unroll
    for (int n = 0; n < 4; ++n) {
        const int gc = cbase + n * 16;
        const float bv = bias[gc];
        float dec = 0.f;
        if constexpr (EPI == 2) dec = __expf(-0.1f / tau[gc]);
        #pragma unroll
        for (int m = 0; m < 2; ++m) {
            #pragma unroll
            for (int r = 0; r < 4; ++r) {
                const int gr = rbase + m * 16 + r;
                float v = acc[m][n][r] + bv;
                if constexpr (EPI == 1) {
                    float tv = 1.0f - 2.0f / (1.0f + __expf(2.0f * v));
                    outB[(size_t)gr * N + gc] = (bf16)tv;
                } else if constexpr (EPI == 2) {
                    float a = 1.0f / (1.0f + __expf(-v));
                    float s = states[(size_t)gr * N + gc];
                    outF[(size_t)gr * N + gc] = a + (s - a) * dec;
                } else {
                    outF[(size_t)gr * N + gc] = v;
                }
            }
        }
    }
}

extern "C" void kernel_launch(void* const* d_in, const int* in_sizes, int n_in,
                              void* d_out, int out_size, void* d_ws, size_t ws_size,
                              hipStream_t stream) {
    const float* x        = (const float*)d_in[0];
    const float* w_in     = (const float*)d_in[1];
    const float* b_in     = (const float*)d_in[2];
    const float* sens_w   = (const float*)d_in[3];
    const float* sens_sig = (const float*)d_in[4];
    const float* tau      = (const float*)d_in[5];
    const float* ro_w     = (const float*)d_in[6];
    const float* ro_b     = (const float*)d_in[7];
    const float* states   = (const float*)d_in[8];

    float* out    = (float*)d_out;                       // [B][D_OUT] (final, GEMM3)
    float* new_st = out + (size_t)BATCH * D_OUT;         // [B][UNITS] (final, GEMM2)
    bf16*  proj   = (bf16*)d_out;                        // temp bf16 in half1

    bf16* w_in_bf = (bf16*)d_ws;                         // 512*1024
    bf16* sensT   = w_in_bf + (size_t)UNITS * D_IN;      // 512*512 (transposed)
    bf16* ro_bf   = sensT + (size_t)UNITS * UNITS;       // 512*512

    // fused weight prep (single launch)
    k_prep<<<1024, 256, 0, stream>>>(w_in, sens_w, ro_w, w_in_bf, sensT, ro_bf);

    // GEMM1: proj = tanh(x @ w_in^T + b_in) -> bf16 (half1, temp); fp32 A via gll16+swizzle
    k_gemm<1024, 1, true><<<(BATCH / 128) * (UNITS / 128), 512, 0, stream>>>(
        x, nullptr, w_in_bf, b_in, nullptr, nullptr, nullptr, proj, BATCH, UNITS);

    // GEMM2: new_st = sig(proj @ sensT^T + sigma); ODE step -> fp32 (half2, final)
    k_gemm<512, 2, false><<<(BATCH / 128) * (UNITS / 128), 512, 0, stream>>>(
        nullptr, proj, sensT, sens_sig, tau, states, new_st, nullptr, BATCH, UNITS);

    // GEMM3: out = new_st @ readout^T + ro_b -> fp32 (half1, final; overwrites dead proj)
    k_gemm<512, 3, true><<<(BATCH / 128) * (D_OUT / 128), 512, 0, stream>>>(
        new_st, nullptr, ro_bf, ro_b, nullptr, nullptr, out, nullptr, BATCH, D_OUT);
}

// Round 5
// 79.642 us; speedup vs baseline: 1.1250x; 1.1250x over previous
//
#include <hip/hip_runtime.h>
#include <stdint.h>
#include <math.h>

typedef __bf16 bf16;
typedef __bf16 bf16x8 __attribute__((ext_vector_type(8)));
typedef __bf16 bf16x4 __attribute__((ext_vector_type(4)));
typedef float f32x4 __attribute__((ext_vector_type(4)));

static constexpr int BATCH = 16384;
static constexpr int D_IN  = 1024;
static constexpr int UNITS = 512;
static constexpr int D_OUT = 512;

__device__ __forceinline__ void gll16(const void* g, void* l) {
    __builtin_amdgcn_global_load_lds(
        (const __attribute__((address_space(1))) void*)g,
        (__attribute__((address_space(3))) void*)l,
        16, 0, 0);
}

// counted vmcnt wait (lgkm/exp = no-wait); N must be < 16
template<int N>
__device__ __forceinline__ void waitvm() {
    static_assert(N < 16, "vmcnt imm");
    __builtin_amdgcn_s_waitcnt(0x0F70 | N);
    asm volatile("" ::: "memory");
}
__device__ __forceinline__ void barrier_raw() {
    asm volatile("" ::: "memory");
    __builtin_amdgcn_s_barrier();
    asm volatile("" ::: "memory");
}

// ---------------- fused weight prep: one launch ----------------
__global__ __launch_bounds__(256)
void k_prep(const float* __restrict__ w_in, const float* __restrict__ sens_w,
            const float* __restrict__ ro_w,
            bf16* __restrict__ w_in_bf, bf16* __restrict__ sensT, bf16* __restrict__ ro_bf)
{
    __shared__ float tile[32][33];
    const int b = blockIdx.x;
    const int t = threadIdx.x;
    if (b < 512) {
        int i = b * 256 + t;
        f32x4 v = ((const f32x4*)w_in)[i];
        bf16x4 o = { (bf16)v.x, (bf16)v.y, (bf16)v.z, (bf16)v.w };
        ((bf16x4*)w_in_bf)[i] = o;
    } else if (b < 768) {
        int bb = b - 512;
        int bx = bb & 15, by = bb >> 4;
        int tx = t & 31, ty = t >> 5;
        #pragma unroll
        for (int j = ty; j < 32; j += 8)
            tile[j][tx] = sens_w[(size_t)(by * 32 + j) * UNITS + bx * 32 + tx];
        __syncthreads();
        #pragma unroll
        for (int j = ty; j < 32; j += 8)
            sensT[(size_t)(bx * 32 + j) * UNITS + by * 32 + tx] = (bf16)tile[tx][j];
    } else {
        int i = (b - 768) * 256 + t;
        f32x4 v = ((const f32x4*)ro_w)[i];
        bf16x4 o = { (bf16)v.x, (bf16)v.y, (bf16)v.z, (bf16)v.w };
        ((bf16x4*)ro_bf)[i] = o;
    }
}

// ---------------- fused GEMM, 8 waves, 3-deep counted-vmcnt pipeline ----------------
// C[M,N] = epilogue( A[M,K] @ Bw[N,K]^T + bias )
// LDS ring of 3 tiles; raw s_barrier + counted vmcnt (never 0 in steady state)
// so prefetch DMA spans barriers (T3/T4, m218). XOR bank-swizzles per rule 21:
//   bf16 operands: slot(16B) ^= (row>>1)&3  (8-way -> 2-way on ds_read_b128)
//   fp32 A:        slot(16B) ^= row&7       (32-way -> 2-way)
// EPI 1: out_bf16 = tanh(.)   EPI 2: sigmoid + ODE decay   EPI 3: identity
template<int K, int EPI, bool AF32>
__global__ __launch_bounds__(512, 4)
void k_gemm(const float* __restrict__ Af, const bf16* __restrict__ Ab,
            const bf16* __restrict__ Bw,
            const float* __restrict__ bias,
            const float* __restrict__ tau,
            const float* __restrict__ states,
            float* __restrict__ outF, bf16* __restrict__ outB,
            int M, int N)
{
    constexpr int NSTEP = K / 32;
    constexpr int L = AF32 ? 3 : 2;                  // gll16 per thread per stage
    constexpr int ABPB = AF32 ? (128 * 32 * 4) : (128 * 32 * 2);
    __shared__ __align__(16) char sAraw[3][ABPB];
    __shared__ bf16 sB[3][128 * 32];

    const int t = threadIdx.x;
    const int ntiles = N >> 7;
    const int nwg = gridDim.x;
    const int d = blockIdx.x;
    const int bid = (d & 7) * (nwg >> 3) + (d >> 3);  // XCD swizzle (nwg%8==0)
    const int mtile = bid / ntiles;
    const int ntile = bid % ntiles;
    const int m0 = mtile << 7, n0 = ntile << 7;

    const int lane = t & 63;
    const int wave = t >> 6;            // 0..7 -> 4m x 2n sub-tiles of 32x64
    const int wr = (wave >> 1) * 32;
    const int wc = (wave & 1) * 64;
    const int l15 = lane & 15;
    const int lk  = (lane >> 4) * 8;    // k-elem offset of this lane's frag

    f32x4 acc[2][4];
    #pragma unroll
    for (int m = 0; m < 2; ++m)
        #pragma unroll
        for (int n = 0; n < 4; ++n)
            acc[m][n] = (f32x4){0.f, 0.f, 0.f, 0.f};

    // ---- staging source addresses (pre-swizzled global per rule 21) ----
    const int brow = t >> 2;
    const int bslot8 = ((t & 3) ^ ((brow >> 1) & 3)) * 8;      // bf16 elems
    const bf16* bbp = Bw + (size_t)(n0 + brow) * K + bslot8;
    const bf16* abp = AF32 ? nullptr : (Ab + (size_t)(m0 + brow) * K + bslot8);
    const int ar = t >> 3;
    const int aslot16 = ((t & 7) ^ (ar & 7)) * 16;             // bytes
    const char* ag0 = (const char*)Af + (size_t)(m0 + ar) * K * 4 + aslot16;
    const char* ag1 = (const char*)Af + (size_t)(m0 + 64 + ar) * K * 4 + aslot16;

    auto STAGE = [&](int buf, int kt) {
        if constexpr (AF32) {
            gll16(ag0 + (size_t)kt * 4, &sAraw[buf][t * 16]);
            gll16(ag1 + (size_t)kt * 4, &sAraw[buf][8192 + t * 16]);
        } else {
            gll16(abp + kt, &sAraw[buf][t * 16]);
        }
        gll16(bbp + kt, (char*)&sB[buf][0] + t * 16);
    };

    // ---- LDS read offsets (swizzled to match staged layout) ----
    int offB[4];
    #pragma unroll
    for (int n = 0; n < 4; ++n) {
        const int R = wc + n * 16 + l15;
        offB[n] = R * 64 + ((lk * 2) ^ (((R >> 1) & 3) << 4));
    }
    int offA0[2], offA1[2];
    #pragma unroll
    for (int m = 0; m < 2; ++m) {
        const int R = wr + m * 16 + l15;
        if constexpr (AF32) {
            const int s = (R & 7) << 4;
            offA0[m] = R * 128 + ((lk * 4) ^ s);
            offA1[m] = R * 128 + ((lk * 4 + 16) ^ s);
        } else {
            offA0[m] = R * 64 + ((lk * 2) ^ (((R >> 1) & 3) << 4));
        }
    }

    auto COMPUTE = [&](int buf) {
        const char* aB = &sAraw[buf][0];
        const char* bB = (const char*)&sB[buf][0];
        bf16x8 afr[2], bfr[4];
        if constexpr (AF32) {
            #pragma unroll
            for (int m = 0; m < 2; ++m) {
                f32x4 h0 = *(const f32x4*)(aB + offA0[m]);
                f32x4 h1 = *(const f32x4*)(aB + offA1[m]);
                afr[m] = (bf16x8){ (bf16)h0.x, (bf16)h0.y, (bf16)h0.z, (bf16)h0.w,
                                   (bf16)h1.x, (bf16)h1.y, (bf16)h1.z, (bf16)h1.w };
            }
        } else {
            #pragma unroll
            for (int m = 0; m < 2; ++m)
                afr[m] = *(const bf16x8*)(aB + offA0[m]);
        }
        #pragma unroll
        for (int n = 0; n < 4; ++n)
            bfr[n] = *(const bf16x8*)(bB + offB[n]);
        #pragma unroll
        for (int m = 0; m < 2; ++m)
            #pragma unroll
            for (int n = 0; n < 4; ++n)
                acc[m][n] = __builtin_amdgcn_mfma_f32_16x16x32_bf16(
                                afr[m], bfr[n], acc[m][n], 0, 0, 0);
    };

    // ---- prologue: fill the 3-deep ring ----
    STAGE(0, 0);
    STAGE(1, 32);
    STAGE(2, 64);

    // ---- steady state: wait tile i (2L still in flight), compute, restage ----
    int buf = 0;
    int kt_stage = 96;
    for (int i = 0; i < NSTEP - 2; ++i) {
        waitvm<2 * L>();
        barrier_raw();
        COMPUTE(buf);
        barrier_raw();
        if (kt_stage < K) { STAGE(buf, kt_stage); kt_stage += 32; }
        buf = (buf == 2) ? 0 : buf + 1;
    }
    // ---- tail: drain with exact counts ----
    waitvm<L>();
    barrier_raw();
    COMPUTE(buf);
    buf = (buf == 2) ? 0 : buf + 1;
    waitvm<0>();
    barrier_raw();
    COMPUTE(buf);
    asm volatile("" ::: "memory");

    // epilogue: D row = wr + 4*(lane>>4) + r (+16m), col = wc + l15 (+16n)
    const int rbase = m0 + wr + ((lane >> 4) << 2);
    const int cbase = n0 + wc + l15;
    #pragma unroll
    for (int n = 0; n < 4; ++n) {
        const int gc = cbase + n * 16;
        const float bv = bias[gc];
        float dec = 0.f;
        if constexpr (EPI == 2) dec = __expf(-0.1f / tau[gc]);
        #pragma unroll
        for (int m = 0; m < 2; ++m) {
            #pragma unroll
            for (int r = 0; r < 4; ++r) {
                const int gr = rbase + m * 16 + r;
                float v = acc[m][n][r] + bv;
                if constexpr (EPI == 1) {
                    float tv = 1.0f - 2.0f / (1.0f + __expf(2.0f * v));
                    outB[(size_t)gr * N + gc] = (bf16)tv;
                } else if constexpr (EPI == 2) {
                    float a = 1.0f / (1.0f + __expf(-v));
                    float s = states[(size_t)gr * N + gc];
                    outF[(size_t)gr * N + gc] = a + (s - a) * dec;
                } else {
                    outF[(size_t)gr * N + gc] = v;
                }
            }
        }
    }
}

extern "C" void kernel_launch(void* const* d_in, const int* in_sizes, int n_in,
                              void* d_out, int out_size, void* d_ws, size_t ws_size,
                              hipStream_t stream) {
    const float* x        = (const float*)d_in[0];
    const float* w_in     = (const float*)d_in[1];
    const float* b_in     = (const float*)d_in[2];
    const float* sens_w   = (const float*)d_in[3];
    const float* sens_sig = (const float*)d_in[4];
    const float* tau      = (const float*)d_in[5];
    const float* ro_w     = (const float*)d_in[6];
    const float* ro_b     = (const float*)d_in[7];
    const float* states   = (const float*)d_in[8];

    float* out    = (float*)d_out;                       // [B][D_OUT] (final, GEMM3)
    float* new_st = out + (size_t)BATCH * D_OUT;         // [B][UNITS] (final, GEMM2)
    bf16*  proj   = (bf16*)d_out;                        // temp bf16 in half1

    bf16* w_in_bf = (bf16*)d_ws;                         // 512*1024
    bf16* sensT   = w_in_bf + (size_t)UNITS * D_IN;      // 512*512 (transposed)
    bf16* ro_bf   = sensT + (size_t)UNITS * UNITS;       // 512*512

    // fused weight prep (single launch)
    k_prep<<<1024, 256, 0, stream>>>(w_in, sens_w, ro_w, w_in_bf, sensT, ro_bf);

    // GEMM1: proj = tanh(x @ w_in^T + b_in) -> bf16 (half1, temp); fp32 A via gll16+swizzle
    k_gemm<1024, 1, true><<<(BATCH / 128) * (UNITS / 128), 512, 0, stream>>>(
        x, nullptr, w_in_bf, b_in, nullptr, nullptr, nullptr, proj, BATCH, UNITS);

    // GEMM2: new_st = sig(proj @ sensT^T + sigma); ODE step -> fp32 (half2, final)
    k_gemm<512, 2, false><<<(BATCH / 128) * (UNITS / 128), 512, 0, stream>>>(
        nullptr, proj, sensT, sens_sig, tau, states, new_st, nullptr, BATCH, UNITS);

    // GEMM3: out = new_st @ readout^T + ro_b -> fp32 (half1, final; overwrites dead proj)
    k_gemm<512, 3, true><<<(BATCH / 128) * (D_OUT / 128), 512, 0, stream>>>(
        new_st, nullptr, ro_bf, ro_b, nullptr, nullptr, out, nullptr, BATCH, D_OUT);
}